// Round 1
// baseline (395.333 us; speedup 1.0000x reference)
//
#include <hip/hip_runtime.h>
#include <stdint.h>

// EdgeNetwork per-edge MLP — round 8: per-mt pipeline for occupancy.
//  Theory: r7 was latency-bound at 2 waves/SIMD (112 arch VGPR + ~64 AGPR
//  accumulators in the unified gfx950 file ≈ 176+ total). Restructure:
//   (a) process one 16-edge mt at a time: acc 64->16 regs, afr 80->20 regs,
//       next-mt gather issued before the epilogue (lands under ~700cy of
//       epilogue VALU) — peak live ~125 regs
//   (b) __launch_bounds__(256,4): 4 blocks/CU (LDS 39936*4 = 159744 fits)
//   (c) eC[] regs dropped — edge-attr index recomputed at issue time;
//       only src/dst index prefetch kept (8+8 regs)
//   (d) grid 1024->2048 for retire-backfill load balancing
//  Cost: W1T B-fragments re-read per mt (80 vs 20 ds_read_b128/tile-wave),
//  ~2-way conflicts = free; LDS pipe stays far under the VALU budget.

#define TPB 256
#define NEG_SLOPE 0.1f
#define LN_EPS    1e-5f

typedef __attribute__((ext_vector_type(8))) short short8;   // 8 bf16 (4 VGPR)
typedef __attribute__((ext_vector_type(4))) float f32x4;    // 4 f32

__device__ __forceinline__ uint32_t fb(float x) {
  union { float f; uint32_t u; } c; c.f = x; return c.u;
}
__device__ __forceinline__ float bf(uint32_t x) {
  union { uint32_t u; float f; } c; c.u = x; return c.f;
}
// pack 2 f32 -> 2 bf16 (round-half-up) in one v_perm after two adds
__device__ __forceinline__ uint32_t pkbf(float a, float b) {
  return __builtin_amdgcn_perm(fb(b) + 0x8000u, fb(a) + 0x8000u, 0x07060302u);
}
__device__ __forceinline__ short8 cvt8(f32x4 a, f32x4 b) {
  union { short8 s; uint32_t u[4]; } r;
  r.u[0] = pkbf(a[0], a[1]);
  r.u[1] = pkbf(a[2], a[3]);
  r.u[2] = pkbf(b[0], b[1]);
  r.u[3] = pkbf(b[2], b[3]);
  return r.s;
}
__device__ __forceinline__ short bf16rne(float x) {   // staging (one-time)
  uint32_t u = fb(x);
  return (short)((u + 0x7fffu + ((u >> 16) & 1u)) >> 16);
}

// DPP rotation-allreduce across each row of 16 lanes (pure VALU).
template <int CTRL>
__device__ __forceinline__ float dppadd(float v) {
  int r = __builtin_amdgcn_update_dpp(0, (int)fb(v), CTRL, 0xf, 0xf, true);
  return v + bf((uint32_t)r);
}
__device__ __forceinline__ float rowsum16(float v) {
  v = dppadd<0x121>(v);   // row_ror:1
  v = dppadd<0x122>(v);   // row_ror:2
  v = dppadd<0x124>(v);   // row_ror:4
  v = dppadd<0x128>(v);   // row_ror:8
  return v;
}
__device__ __forceinline__ void redsum16(f32x4& v) {
  #pragma unroll
  for (int c = 0; c < 4; ++c) v[c] = rowsum16(v[c]);
}

__global__ __launch_bounds__(TPB, 4)
void edge_mlp_mfma(const float* __restrict__ nf, const int* __restrict__ ei,
                   const float* __restrict__ ea,
                   const float* __restrict__ W1, const float* __restrict__ b1,
                   const float* __restrict__ g1, const float* __restrict__ be1,
                   const float* __restrict__ W2, const float* __restrict__ b2,
                   const float* __restrict__ g2, const float* __restrict__ be2,
                   const float* __restrict__ W3, const float* __restrict__ b3,
                   float* __restrict__ out, int E, int ntiles) {
  __shared__ short W1T[64 * 168];      // [n][k], k 0..159 (144 real + 16 zero)
  __shared__ short W2T[64 * 72];       // [n][k], stride 72
  __shared__ short HB[4][16 * 72];     // per-wave h1 tile (16 edges x 64 + pad)

  const int tid  = threadIdx.x;
  const int lane = tid & 63;
  const int wv   = tid >> 6;
  const int ln   = lane & 15;
  const int quad = lane >> 4;

  // ---- Stage W1^T, W2^T as bf16 into LDS ----
  for (int i = tid; i < 9216; i += TPB) {
    int n = i & 63, k = i >> 6;
    W1T[n * 168 + k] = bf16rne(W1[k * 64 + n]);
  }
  for (int i = tid; i < 1024; i += TPB) {            // zero-pad k in [144,160)
    int n = i & 63, k = 144 + (i >> 6);
    W1T[n * 168 + k] = 0;
  }
  for (int i = tid; i < 4096; i += TPB) {
    int n = i & 63, k = i >> 6;
    W2T[n * 72 + k] = bf16rne(W2[k * 64 + n]);
  }
  __syncthreads();   // the ONLY block barrier

  // ---- Per-lane n-indexed params (n = ln + 16*jt) ----
  float b1v[4], g1v[4], be1v[4], b2v[4], g2v[4], be2v[4], W3v[4];
  #pragma unroll
  for (int jt = 0; jt < 4; ++jt) {
    int n = ln + 16 * jt;
    b1v[jt] = b1[n];  g1v[jt] = g1[n];  be1v[jt] = be1[n];
    b2v[jt] = b2[n];  g2v[jt] = g2[n];  be2v[jt] = be2[n];
    W3v[jt] = W3[n];
  }
  const float b3s = b3[0];

  // int64-vs-int32 index sniff (validated rounds 3-7)
  const bool idx64 = (__ballot(ei[2 * lane + 1] == 0) == ~0ull);

  // ---- Indices: current tile (sI/dI) and next tile (sN/dN) ----
  int sI[4], dI[4], sN[4], dN[4];
  {
    const int eb0 = blockIdx.x * 256 + wv * 64;
    #pragma unroll
    for (int mt = 0; mt < 4; ++mt) {
      int el = eb0 + mt * 16 + ln;
      int ec = el < E ? el : E - 1;
      if (idx64) { sI[mt] = ei[2 * ec]; dI[mt] = ei[2 * (E + ec)]; }
      else       { sI[mt] = ei[ec];     dI[mt] = ei[E + ec]; }
      sN[mt] = sI[mt]; dN[mt] = dI[mt];   // safe defaults for the last tile
    }
  }

  // ---- Gather in-flight buffer (one mt's worth) ----
  f32x4 raw[10];
  auto issue = [&](int s, int d, int el) {
    int ec = el < E ? el : E - 1;
    const float* sp = nf + (size_t)s * 64 + quad * 8;
    const float* dp = nf + (size_t)d * 64 + quad * 8;
    const float* ap = ea + (size_t)ec * 16 + (quad & 1) * 8;
    raw[0] = *(const f32x4*)sp;        raw[1] = *(const f32x4*)(sp + 4);
    raw[2] = *(const f32x4*)(sp + 32); raw[3] = *(const f32x4*)(sp + 36);
    raw[4] = *(const f32x4*)dp;        raw[5] = *(const f32x4*)(dp + 4);
    raw[6] = *(const f32x4*)(dp + 32); raw[7] = *(const f32x4*)(dp + 36);
    raw[8] = *(const f32x4*)ap;        raw[9] = *(const f32x4*)(ap + 4);
  };

  // prologue: first mt's gather in flight
  issue(sI[0], dI[0], blockIdx.x * 256 + wv * 64 + ln);

  for (int tile = blockIdx.x; tile < ntiles; tile += gridDim.x) {
    const int ebase = tile * 256 + wv * 64;

    #pragma unroll
    for (int mt = 0; mt < 4; ++mt) {
      // ---- convert landed gather to bf16 A-fragments (frees raw[]) ----
      short8 afr[5];
      afr[0] = cvt8(raw[0], raw[1]);
      afr[1] = cvt8(raw[2], raw[3]);
      afr[2] = cvt8(raw[4], raw[5]);
      afr[3] = cvt8(raw[6], raw[7]);
      afr[4] = cvt8(raw[8], raw[9]);   // k>=144 lanes: B rows zero, value moot

      // ---- Layer 1: 20 MFMAs (bias pre-folded into acc init) ----
      f32x4 acc[4];                    // [jt] — 16 regs, not 64
      #pragma unroll
      for (int jt = 0; jt < 4; ++jt) acc[jt] = (f32x4)(b1v[jt]);

      #pragma unroll
      for (int t = 0; t < 5; ++t)
        #pragma unroll
        for (int jt = 0; jt < 4; ++jt) {
          short8 bfr = *(const short8*)&W1T[(jt * 16 + ln) * 168 + t * 32 + quad * 8];
          acc[jt] = __builtin_amdgcn_mfma_f32_16x16x32_bf16(
              afr[t], bfr, acc[jt], 0, 0, 0);
        }

      // ---- Prefetch next tile's indices (consumed at mt==3; ~2 epilogues) --
      if (mt == 1) {
        int ntile = tile + gridDim.x;
        if (ntile < ntiles) {
          const int nb = ntile * 256 + wv * 64;
          #pragma unroll
          for (int m2 = 0; m2 < 4; ++m2) {
            int el = nb + m2 * 16 + ln;
            int ec = el < E ? el : E - 1;
            if (idx64) { sN[m2] = ei[2 * ec]; dN[m2] = ei[2 * (E + ec)]; }
            else       { sN[m2] = ei[ec];     dN[m2] = ei[E + ec]; }
          }
        }
      }

      // ---- Issue next mt's gather: latency hides under this epilogue ----
      if (mt < 3) issue(sI[mt + 1], dI[mt + 1], ebase + (mt + 1) * 16 + ln);
      else        issue(sN[0], dN[0], (tile + (int)gridDim.x) * 256 + wv * 64 + ln);

      // ---- Epilogue (wave-private; DPP reductions, no block barriers) ----
      f32x4 sv = acc[0] + acc[1] + acc[2] + acc[3];
      f32x4 qv = acc[0] * acc[0] + acc[1] * acc[1]
               + acc[2] * acc[2] + acc[3] * acc[3];
      redsum16(sv);
      redsum16(qv);
      f32x4 mu  = sv * (1.f / 64.f);
      f32x4 var = qv * (1.f / 64.f) - mu * mu;
      f32x4 rs;
      rs[0] = rsqrtf(var[0] + LN_EPS); rs[1] = rsqrtf(var[1] + LN_EPS);
      rs[2] = rsqrtf(var[2] + LN_EPS); rs[3] = rsqrtf(var[3] + LN_EPS);

      #pragma unroll
      for (int jt = 0; jt < 4; ++jt)
        #pragma unroll
        for (int r = 0; r < 4; ++r) {
          float h = (acc[jt][r] - mu[r]) * rs[r] * g1v[jt] + be1v[jt];
          h = fmaxf(h, NEG_SLOPE * h);
          HB[wv][(quad * 4 + r) * 72 + ln + 16 * jt] =
              (short)((fb(h) + 0x8000u) >> 16);
        }
      // wave-private handoff: DS in-order per wave; drain writes then read
      asm volatile("s_waitcnt lgkmcnt(0)" ::: "memory");

      f32x4 acc2[4];
      #pragma unroll
      for (int jt = 0; jt < 4; ++jt) acc2[jt] = (f32x4)(b2v[jt]);
      #pragma unroll
      for (int t2 = 0; t2 < 2; ++t2) {
        short8 a2 = *(const short8*)&HB[wv][ln * 72 + t2 * 32 + quad * 8];
        #pragma unroll
        for (int jt = 0; jt < 4; ++jt) {
          short8 w2f = *(const short8*)&W2T[(jt * 16 + ln) * 72 + t2 * 32 + quad * 8];
          acc2[jt] = __builtin_amdgcn_mfma_f32_16x16x32_bf16(
              a2, w2f, acc2[jt], 0, 0, 0);
        }
      }

      f32x4 s2 = acc2[0] + acc2[1] + acc2[2] + acc2[3];
      f32x4 q2 = acc2[0] * acc2[0] + acc2[1] * acc2[1]
               + acc2[2] * acc2[2] + acc2[3] * acc2[3];
      redsum16(s2);
      redsum16(q2);
      f32x4 mu2  = s2 * (1.f / 64.f);
      f32x4 var2 = q2 * (1.f / 64.f) - mu2 * mu2;
      f32x4 rs2;
      rs2[0] = rsqrtf(var2[0] + LN_EPS); rs2[1] = rsqrtf(var2[1] + LN_EPS);
      rs2[2] = rsqrtf(var2[2] + LN_EPS); rs2[3] = rsqrtf(var2[3] + LN_EPS);

      f32x4 po = (f32x4)0.f;
      #pragma unroll
      for (int jt = 0; jt < 4; ++jt)
        #pragma unroll
        for (int r = 0; r < 4; ++r) {
          float h = (acc2[jt][r] - mu2[r]) * rs2[r] * g2v[jt] + be2v[jt];
          h = fmaxf(h, NEG_SLOPE * h);
          po[r] = fmaf(h, W3v[jt], po[r]);
        }
      redsum16(po);

      if (ln < 4) {       // lanes 0-3 of each quad store edges quad*4 + ln
        int e = ebase + mt * 16 + quad * 4 + ln;
        if (e < E) {
          float v = (ln == 0) ? po[0] : (ln == 1) ? po[1] : (ln == 2) ? po[2] : po[3];
          out[e] = v + b3s;
        }
      }
    }

    // rotate next-tile indices into place
    #pragma unroll
    for (int m2 = 0; m2 < 4; ++m2) { sI[m2] = sN[m2]; dI[m2] = dN[m2]; }
  }
}

extern "C" void kernel_launch(void* const* d_in, const int* in_sizes, int n_in,
                              void* d_out, int out_size, void* d_ws, size_t ws_size,
                              hipStream_t stream) {
  const float* nf = (const float*)d_in[0];
  const int*   ei = (const int*)d_in[1];
  const float* ea = (const float*)d_in[2];

  const int E = out_size;
  const int ntiles = (E + 255) / 256;
  const int blocks = ntiles < 2048 ? ntiles : 2048;

  edge_mlp_mfma<<<blocks, TPB, 0, stream>>>(
      nf, ei, ea,
      (const float*)d_in[3],  (const float*)d_in[4],
      (const float*)d_in[5],  (const float*)d_in[6],
      (const float*)d_in[7],  (const float*)d_in[8],
      (const float*)d_in[9],  (const float*)d_in[10],
      (const float*)d_in[11], (const float*)d_in[12],
      (float*)d_out, E, ntiles);
}

// Round 2
// 297.244 us; speedup vs baseline: 1.3300x; 1.3300x over previous
//
#include <hip/hip_runtime.h>
#include <stdint.h>

// EdgeNetwork per-edge MLP — round 9: per-mt pipeline at 3 waves/SIMD.
//  r8 post-mortem: __launch_bounds__(256,4) (128-reg cap) forced ~45 regs of
//  scratch spill in the hot loop (WRITE_SIZE 6.4->174 MB, FETCH +242 MB) —
//  occupancy doubled but spill traffic cost more than latency hiding gained.
//  r9: same per-mt pipelined structure, __launch_bounds__(256,3) -> ~170-reg
//  budget, which fits the measured live set (raw[10]=40 held through epilogue
//  + acc/acc2 32 + params 29 + indices 16 + addressing) with no spills.
//  LDS 39936*3 = 119808 < 160K so 3 blocks/CU stand.
//  Roofline context: HBM floor ~55us (348MB @ 6.3TB/s), VALU-issue floor
//  ~40us -> r7's 197us is latency-bound; occupancy is the remaining lever.

#define TPB 256
#define NEG_SLOPE 0.1f
#define LN_EPS    1e-5f

typedef __attribute__((ext_vector_type(8))) short short8;   // 8 bf16 (4 VGPR)
typedef __attribute__((ext_vector_type(4))) float f32x4;    // 4 f32

__device__ __forceinline__ uint32_t fb(float x) {
  union { float f; uint32_t u; } c; c.f = x; return c.u;
}
__device__ __forceinline__ float bf(uint32_t x) {
  union { uint32_t u; float f; } c; c.u = x; return c.f;
}
// pack 2 f32 -> 2 bf16 (round-half-up) in one v_perm after two adds
__device__ __forceinline__ uint32_t pkbf(float a, float b) {
  return __builtin_amdgcn_perm(fb(b) + 0x8000u, fb(a) + 0x8000u, 0x07060302u);
}
__device__ __forceinline__ short8 cvt8(f32x4 a, f32x4 b) {
  union { short8 s; uint32_t u[4]; } r;
  r.u[0] = pkbf(a[0], a[1]);
  r.u[1] = pkbf(a[2], a[3]);
  r.u[2] = pkbf(b[0], b[1]);
  r.u[3] = pkbf(b[2], b[3]);
  return r.s;
}
__device__ __forceinline__ short bf16rne(float x) {   // staging (one-time)
  uint32_t u = fb(x);
  return (short)((u + 0x7fffu + ((u >> 16) & 1u)) >> 16);
}

// DPP rotation-allreduce across each row of 16 lanes (pure VALU).
template <int CTRL>
__device__ __forceinline__ float dppadd(float v) {
  int r = __builtin_amdgcn_update_dpp(0, (int)fb(v), CTRL, 0xf, 0xf, true);
  return v + bf((uint32_t)r);
}
__device__ __forceinline__ float rowsum16(float v) {
  v = dppadd<0x121>(v);   // row_ror:1
  v = dppadd<0x122>(v);   // row_ror:2
  v = dppadd<0x124>(v);   // row_ror:4
  v = dppadd<0x128>(v);   // row_ror:8
  return v;
}
__device__ __forceinline__ void redsum16(f32x4& v) {
  #pragma unroll
  for (int c = 0; c < 4; ++c) v[c] = rowsum16(v[c]);
}

__global__ __launch_bounds__(TPB, 3)
void edge_mlp_mfma(const float* __restrict__ nf, const int* __restrict__ ei,
                   const float* __restrict__ ea,
                   const float* __restrict__ W1, const float* __restrict__ b1,
                   const float* __restrict__ g1, const float* __restrict__ be1,
                   const float* __restrict__ W2, const float* __restrict__ b2,
                   const float* __restrict__ g2, const float* __restrict__ be2,
                   const float* __restrict__ W3, const float* __restrict__ b3,
                   float* __restrict__ out, int E, int ntiles) {
  __shared__ short W1T[64 * 168];      // [n][k], k 0..159 (144 real + 16 zero)
  __shared__ short W2T[64 * 72];       // [n][k], stride 72
  __shared__ short HB[4][16 * 72];     // per-wave h1 tile (16 edges x 64 + pad)

  const int tid  = threadIdx.x;
  const int lane = tid & 63;
  const int wv   = tid >> 6;
  const int ln   = lane & 15;
  const int quad = lane >> 4;

  // ---- Stage W1^T, W2^T as bf16 into LDS ----
  for (int i = tid; i < 9216; i += TPB) {
    int n = i & 63, k = i >> 6;
    W1T[n * 168 + k] = bf16rne(W1[k * 64 + n]);
  }
  for (int i = tid; i < 1024; i += TPB) {            // zero-pad k in [144,160)
    int n = i & 63, k = 144 + (i >> 6);
    W1T[n * 168 + k] = 0;
  }
  for (int i = tid; i < 4096; i += TPB) {
    int n = i & 63, k = i >> 6;
    W2T[n * 72 + k] = bf16rne(W2[k * 64 + n]);
  }
  __syncthreads();   // the ONLY block barrier

  // ---- Per-lane n-indexed params (n = ln + 16*jt) ----
  float b1v[4], g1v[4], be1v[4], b2v[4], g2v[4], be2v[4], W3v[4];
  #pragma unroll
  for (int jt = 0; jt < 4; ++jt) {
    int n = ln + 16 * jt;
    b1v[jt] = b1[n];  g1v[jt] = g1[n];  be1v[jt] = be1[n];
    b2v[jt] = b2[n];  g2v[jt] = g2[n];  be2v[jt] = be2[n];
    W3v[jt] = W3[n];
  }
  const float b3s = b3[0];

  // int64-vs-int32 index sniff (validated rounds 3-8)
  const bool idx64 = (__ballot(ei[2 * lane + 1] == 0) == ~0ull);

  // ---- Indices: current tile (sI/dI) and next tile (sN/dN) ----
  int sI[4], dI[4], sN[4], dN[4];
  {
    const int eb0 = blockIdx.x * 256 + wv * 64;
    #pragma unroll
    for (int mt = 0; mt < 4; ++mt) {
      int el = eb0 + mt * 16 + ln;
      int ec = el < E ? el : E - 1;
      if (idx64) { sI[mt] = ei[2 * ec]; dI[mt] = ei[2 * (E + ec)]; }
      else       { sI[mt] = ei[ec];     dI[mt] = ei[E + ec]; }
      sN[mt] = sI[mt]; dN[mt] = dI[mt];   // safe defaults for the last tile
    }
  }

  // ---- Gather in-flight buffer (one mt's worth) ----
  f32x4 raw[10];
  auto issue = [&](int s, int d, int el) {
    int ec = el < E ? el : E - 1;
    const float* sp = nf + (size_t)s * 64 + quad * 8;
    const float* dp = nf + (size_t)d * 64 + quad * 8;
    const float* ap = ea + (size_t)ec * 16 + (quad & 1) * 8;
    raw[0] = *(const f32x4*)sp;        raw[1] = *(const f32x4*)(sp + 4);
    raw[2] = *(const f32x4*)(sp + 32); raw[3] = *(const f32x4*)(sp + 36);
    raw[4] = *(const f32x4*)dp;        raw[5] = *(const f32x4*)(dp + 4);
    raw[6] = *(const f32x4*)(dp + 32); raw[7] = *(const f32x4*)(dp + 36);
    raw[8] = *(const f32x4*)ap;        raw[9] = *(const f32x4*)(ap + 4);
  };

  // prologue: first mt's gather in flight
  issue(sI[0], dI[0], blockIdx.x * 256 + wv * 64 + ln);

  for (int tile = blockIdx.x; tile < ntiles; tile += gridDim.x) {
    const int ebase = tile * 256 + wv * 64;

    #pragma unroll
    for (int mt = 0; mt < 4; ++mt) {
      // ---- convert landed gather to bf16 A-fragments (frees raw[]) ----
      short8 afr[5];
      afr[0] = cvt8(raw[0], raw[1]);
      afr[1] = cvt8(raw[2], raw[3]);
      afr[2] = cvt8(raw[4], raw[5]);
      afr[3] = cvt8(raw[6], raw[7]);
      afr[4] = cvt8(raw[8], raw[9]);   // k>=144 lanes: B rows zero, value moot

      // ---- Layer 1: 20 MFMAs (bias pre-folded into acc init) ----
      f32x4 acc[4];                    // [jt] — 16 regs, not 64
      #pragma unroll
      for (int jt = 0; jt < 4; ++jt) acc[jt] = (f32x4)(b1v[jt]);

      #pragma unroll
      for (int t = 0; t < 5; ++t)
        #pragma unroll
        for (int jt = 0; jt < 4; ++jt) {
          short8 bfr = *(const short8*)&W1T[(jt * 16 + ln) * 168 + t * 32 + quad * 8];
          acc[jt] = __builtin_amdgcn_mfma_f32_16x16x32_bf16(
              afr[t], bfr, acc[jt], 0, 0, 0);
        }

      // ---- Prefetch next tile's indices (consumed at mt==3; ~2 epilogues) --
      if (mt == 1) {
        int ntile = tile + gridDim.x;
        if (ntile < ntiles) {
          const int nb = ntile * 256 + wv * 64;
          #pragma unroll
          for (int m2 = 0; m2 < 4; ++m2) {
            int el = nb + m2 * 16 + ln;
            int ec = el < E ? el : E - 1;
            if (idx64) { sN[m2] = ei[2 * ec]; dN[m2] = ei[2 * (E + ec)]; }
            else       { sN[m2] = ei[ec];     dN[m2] = ei[E + ec]; }
          }
        }
      }

      // ---- Issue next mt's gather: latency hides under this epilogue ----
      if (mt < 3) issue(sI[mt + 1], dI[mt + 1], ebase + (mt + 1) * 16 + ln);
      else        issue(sN[0], dN[0], (tile + (int)gridDim.x) * 256 + wv * 64 + ln);

      // ---- Epilogue (wave-private; DPP reductions, no block barriers) ----
      f32x4 sv = acc[0] + acc[1] + acc[2] + acc[3];
      f32x4 qv = acc[0] * acc[0] + acc[1] * acc[1]
               + acc[2] * acc[2] + acc[3] * acc[3];
      redsum16(sv);
      redsum16(qv);
      f32x4 mu  = sv * (1.f / 64.f);
      f32x4 var = qv * (1.f / 64.f) - mu * mu;
      f32x4 rs;
      rs[0] = rsqrtf(var[0] + LN_EPS); rs[1] = rsqrtf(var[1] + LN_EPS);
      rs[2] = rsqrtf(var[2] + LN_EPS); rs[3] = rsqrtf(var[3] + LN_EPS);

      #pragma unroll
      for (int jt = 0; jt < 4; ++jt)
        #pragma unroll
        for (int r = 0; r < 4; ++r) {
          float h = (acc[jt][r] - mu[r]) * rs[r] * g1v[jt] + be1v[jt];
          h = fmaxf(h, NEG_SLOPE * h);
          HB[wv][(quad * 4 + r) * 72 + ln + 16 * jt] =
              (short)((fb(h) + 0x8000u) >> 16);
        }
      // wave-private handoff: DS in-order per wave; drain writes then read
      asm volatile("s_waitcnt lgkmcnt(0)" ::: "memory");

      f32x4 acc2[4];
      #pragma unroll
      for (int jt = 0; jt < 4; ++jt) acc2[jt] = (f32x4)(b2v[jt]);
      #pragma unroll
      for (int t2 = 0; t2 < 2; ++t2) {
        short8 a2 = *(const short8*)&HB[wv][ln * 72 + t2 * 32 + quad * 8];
        #pragma unroll
        for (int jt = 0; jt < 4; ++jt) {
          short8 w2f = *(const short8*)&W2T[(jt * 16 + ln) * 72 + t2 * 32 + quad * 8];
          acc2[jt] = __builtin_amdgcn_mfma_f32_16x16x32_bf16(
              a2, w2f, acc2[jt], 0, 0, 0);
        }
      }

      f32x4 s2 = acc2[0] + acc2[1] + acc2[2] + acc2[3];
      f32x4 q2 = acc2[0] * acc2[0] + acc2[1] * acc2[1]
               + acc2[2] * acc2[2] + acc2[3] * acc2[3];
      redsum16(s2);
      redsum16(q2);
      f32x4 mu2  = s2 * (1.f / 64.f);
      f32x4 var2 = q2 * (1.f / 64.f) - mu2 * mu2;
      f32x4 rs2;
      rs2[0] = rsqrtf(var2[0] + LN_EPS); rs2[1] = rsqrtf(var2[1] + LN_EPS);
      rs2[2] = rsqrtf(var2[2] + LN_EPS); rs2[3] = rsqrtf(var2[3] + LN_EPS);

      f32x4 po = (f32x4)0.f;
      #pragma unroll
      for (int jt = 0; jt < 4; ++jt)
        #pragma unroll
        for (int r = 0; r < 4; ++r) {
          float h = (acc2[jt][r] - mu2[r]) * rs2[r] * g2v[jt] + be2v[jt];
          h = fmaxf(h, NEG_SLOPE * h);
          po[r] = fmaf(h, W3v[jt], po[r]);
        }
      redsum16(po);

      if (ln < 4) {       // lanes 0-3 of each quad store edges quad*4 + ln
        int e = ebase + mt * 16 + quad * 4 + ln;
        if (e < E) {
          float v = (ln == 0) ? po[0] : (ln == 1) ? po[1] : (ln == 2) ? po[2] : po[3];
          out[e] = v + b3s;
        }
      }
    }

    // rotate next-tile indices into place
    #pragma unroll
    for (int m2 = 0; m2 < 4; ++m2) { sI[m2] = sN[m2]; dI[m2] = dN[m2]; }
  }
}

extern "C" void kernel_launch(void* const* d_in, const int* in_sizes, int n_in,
                              void* d_out, int out_size, void* d_ws, size_t ws_size,
                              hipStream_t stream) {
  const float* nf = (const float*)d_in[0];
  const int*   ei = (const int*)d_in[1];
  const float* ea = (const float*)d_in[2];

  const int E = out_size;
  const int ntiles = (E + 255) / 256;
  const int blocks = ntiles < 2048 ? ntiles : 2048;

  edge_mlp_mfma<<<blocks, TPB, 0, stream>>>(
      nf, ei, ea,
      (const float*)d_in[3],  (const float*)d_in[4],
      (const float*)d_in[5],  (const float*)d_in[6],
      (const float*)d_in[7],  (const float*)d_in[8],
      (const float*)d_in[9],  (const float*)d_in[10],
      (const float*)d_in[11], (const float*)d_in[12],
      (float*)d_out, E, ntiles);
}

// Round 6
// 289.495 us; speedup vs baseline: 1.3656x; 1.0268x over previous
//
#include <hip/hip_runtime.h>
#include <stdint.h>

// EdgeNetwork per-edge MLP — round 13: bisect conclusion.
//  r12 kept {cvt_pk, pk-math}, reverted fused-DPP -> error UNCHANGED (0.656
//  vs 0.672). Bug is cvt_pk or pk-math. Signature analysis: a cvt_pk hi/lo
//  swap would scramble MFMA k-pairing -> garbage-level error; a pk-math
//  op_sel_hi default mismatch makes the hi lane compute from lo halves ->
//  mu[1]=mu[0], mu[3]=mu[2] -> rows 1,3 of each quad normalized with rows
//  0,2's stats -> O(0.5) logit error = EXACTLY what we see. Verdict: the
//  handwritten V_PK_*_F32 VOP3P asm is the bug (assembler modifier defaults).
//  r13 = r12 with lnstats partial sums reverted to plain C++ vector math
//  (compiler emits packed ops with correct modifiers itself when profitable);
//  KEEPS v_cvt_pk_bf16_f32 (externally validated; order-immune in HB path,
//  and a swap there would error at 100x the observed level).

#define TPB 256
#define NEG_SLOPE 0.1f
#define LN_EPS    1e-5f

typedef __attribute__((ext_vector_type(8))) short short8;   // 8 bf16 (4 VGPR)
typedef __attribute__((ext_vector_type(4))) float f32x4;    // 4 f32

__device__ __forceinline__ uint32_t fb(float x) {
  union { float f; uint32_t u; } c; c.f = x; return c.u;
}
__device__ __forceinline__ float bf(uint32_t x) {
  union { uint32_t u; float f; } c; c.u = x; return c.f;
}
// ---- f32 pair -> packed bf16 (RNE), 1 instr; src0 -> low half ----
__device__ __forceinline__ uint32_t cvtpk(float a, float b) {
  uint32_t r; asm("v_cvt_pk_bf16_f32 %0, %1, %2" : "=v"(r) : "v"(a), "v"(b));
  return r;
}
__device__ __forceinline__ short8 cvt8(f32x4 a, f32x4 b) {
  union { short8 s; uint32_t u[4]; } r;
  r.u[0] = cvtpk(a[0], a[1]);
  r.u[1] = cvtpk(a[2], a[3]);
  r.u[2] = cvtpk(b[0], b[1]);
  r.u[3] = cvtpk(b[2], b[3]);
  return r.s;
}
__device__ __forceinline__ short bf16rne(float x) {   // staging (one-time)
  uint32_t u = fb(x);
  return (short)((u + 0x7fffu + ((u >> 16) & 1u)) >> 16);
}

// DPP rotation-allreduce across each row of 16 lanes (builtin form — the
// compiler inserts required hazard waits; proven correct rounds 7-9).
template <int CTRL>
__device__ __forceinline__ float dppadd(float v) {
  int r = __builtin_amdgcn_update_dpp(0, (int)fb(v), CTRL, 0xf, 0xf, true);
  return v + bf((uint32_t)r);
}
__device__ __forceinline__ float rowsum16(float v) {
  v = dppadd<0x121>(v);   // row_ror:1
  v = dppadd<0x122>(v);   // row_ror:2
  v = dppadd<0x124>(v);   // row_ror:4
  v = dppadd<0x128>(v);   // row_ror:8
  return v;
}
__device__ __forceinline__ void redsum16(f32x4& v) {
  #pragma unroll
  for (int c = 0; c < 4; ++c) v[c] = rowsum16(v[c]);
}

// LN stats over 64 features held as acc[4] (cols ln+16*jt, rows quad*4+r).
// Plain vector math (r9-proven); compiler packs where profitable.
__device__ __forceinline__ void lnstats(const f32x4& a0, const f32x4& a1,
                                        const f32x4& a2, const f32x4& a3,
                                        f32x4& mu, f32x4& rs) {
  f32x4 sv = a0 + a1 + a2 + a3;
  f32x4 qv = a0 * a0 + a1 * a1 + a2 * a2 + a3 * a3;
  redsum16(sv);
  redsum16(qv);
  mu = sv * (1.f / 64.f);
  f32x4 var = qv * (1.f / 64.f) - mu * mu;
  rs[0] = rsqrtf(var[0] + LN_EPS); rs[1] = rsqrtf(var[1] + LN_EPS);
  rs[2] = rsqrtf(var[2] + LN_EPS); rs[3] = rsqrtf(var[3] + LN_EPS);
}

// LDS strides (shorts): must be multiples of 8 shorts (16B) for b128 rows.
#define SW1 168
#define SW2 72

__global__ __launch_bounds__(TPB, 3)
void edge_mlp_mfma(const float* __restrict__ nf, const int* __restrict__ ei,
                   const float* __restrict__ ea,
                   const float* __restrict__ W1, const float* __restrict__ b1,
                   const float* __restrict__ g1, const float* __restrict__ be1,
                   const float* __restrict__ W2, const float* __restrict__ b2,
                   const float* __restrict__ g2, const float* __restrict__ be2,
                   const float* __restrict__ W3, const float* __restrict__ b3,
                   float* __restrict__ out, int E, int ntiles) {
  __shared__ short W1T[64 * SW1];      // [n][k], k 0..159 (144 real + 16 zero)
  __shared__ short W2T[64 * SW2];      // [n][k]
  __shared__ short HB[4][16 * SW2];    // per-wave h1 tile (16 edges x 64)

  const int tid  = threadIdx.x;
  const int lane = tid & 63;
  const int wv   = tid >> 6;
  const int ln   = lane & 15;
  const int quad = lane >> 4;

  // ---- Stage W1^T, W2^T as bf16 into LDS ----
  for (int i = tid; i < 9216; i += TPB) {
    int n = i & 63, k = i >> 6;
    W1T[n * SW1 + k] = bf16rne(W1[k * 64 + n]);
  }
  for (int i = tid; i < 1024; i += TPB) {            // zero-pad k in [144,160)
    int n = i & 63, k = 144 + (i >> 6);
    W1T[n * SW1 + k] = 0;
  }
  for (int i = tid; i < 4096; i += TPB) {
    int n = i & 63, k = i >> 6;
    W2T[n * SW2 + k] = bf16rne(W2[k * 64 + n]);
  }
  __syncthreads();   // the ONLY block barrier

  // ---- Per-lane n-indexed params (n = ln + 16*jt) ----
  float b1v[4], g1v[4], be1v[4], b2v[4], g2v[4], be2v[4], W3v[4];
  #pragma unroll
  for (int jt = 0; jt < 4; ++jt) {
    int n = ln + 16 * jt;
    b1v[jt] = b1[n];  g1v[jt] = g1[n];  be1v[jt] = be1[n];
    b2v[jt] = b2[n];  g2v[jt] = g2[n];  be2v[jt] = be2[n];
    W3v[jt] = W3[n];
  }
  const float b3s = b3[0];

  // int64-vs-int32 index sniff (validated rounds 3-9)
  const bool idx64 = (__ballot(ei[2 * lane + 1] == 0) == ~0ull);

  // ---- Indices: current tile (sI/dI) and next tile (sN/dN) ----
  int sI[4], dI[4], sN[4], dN[4];
  {
    const int eb0 = blockIdx.x * 256 + wv * 64;
    #pragma unroll
    for (int mt = 0; mt < 4; ++mt) {
      int el = eb0 + mt * 16 + ln;
      int ec = el < E ? el : E - 1;
      if (idx64) { sI[mt] = ei[2 * ec]; dI[mt] = ei[2 * (E + ec)]; }
      else       { sI[mt] = ei[ec];     dI[mt] = ei[E + ec]; }
      sN[mt] = sI[mt]; dN[mt] = dI[mt];   // safe defaults for the last tile
    }
  }

  // ---- Gather in-flight buffer (one mt's worth) ----
  f32x4 raw[10];
  auto issue = [&](int s, int d, int el) {
    int ec = el < E ? el : E - 1;
    const float* sp = nf + (size_t)s * 64 + quad * 8;
    const float* dp = nf + (size_t)d * 64 + quad * 8;
    const float* ap = ea + (size_t)ec * 16 + (quad & 1) * 8;
    raw[0] = *(const f32x4*)sp;        raw[1] = *(const f32x4*)(sp + 4);
    raw[2] = *(const f32x4*)(sp + 32); raw[3] = *(const f32x4*)(sp + 36);
    raw[4] = *(const f32x4*)dp;        raw[5] = *(const f32x4*)(dp + 4);
    raw[6] = *(const f32x4*)(dp + 32); raw[7] = *(const f32x4*)(dp + 36);
    raw[8] = *(const f32x4*)ap;        raw[9] = *(const f32x4*)(ap + 4);
  };

  // prologue: first mt's gather in flight
  issue(sI[0], dI[0], blockIdx.x * 256 + wv * 64 + ln);

  for (int tile = blockIdx.x; tile < ntiles; tile += gridDim.x) {
    const int ebase = tile * 256 + wv * 64;

    #pragma unroll
    for (int mt = 0; mt < 4; ++mt) {
      // ---- convert landed gather to bf16 A-fragments (frees raw[]) ----
      short8 afr[5];
      afr[0] = cvt8(raw[0], raw[1]);
      afr[1] = cvt8(raw[2], raw[3]);
      afr[2] = cvt8(raw[4], raw[5]);
      afr[3] = cvt8(raw[6], raw[7]);
      afr[4] = cvt8(raw[8], raw[9]);   // k>=144 lanes: B rows zero, value moot

      // ---- Layer 1: 20 MFMAs (bias pre-folded into acc init) ----
      f32x4 acc[4];                    // [jt]
      #pragma unroll
      for (int jt = 0; jt < 4; ++jt) acc[jt] = (f32x4)(b1v[jt]);

      #pragma unroll
      for (int t = 0; t < 5; ++t)
        #pragma unroll
        for (int jt = 0; jt < 4; ++jt) {
          short8 bfr = *(const short8*)&W1T[(jt * 16 + ln) * SW1 + t * 32 + quad * 8];
          acc[jt] = __builtin_amdgcn_mfma_f32_16x16x32_bf16(
              afr[t], bfr, acc[jt], 0, 0, 0);
        }

      // ---- Prefetch next tile's indices (consumed at mt==3) ----
      if (mt == 1) {
        int ntile = tile + gridDim.x;
        if (ntile < ntiles) {
          const int nb = ntile * 256 + wv * 64;
          #pragma unroll
          for (int m2 = 0; m2 < 4; ++m2) {
            int el = nb + m2 * 16 + ln;
            int ec = el < E ? el : E - 1;
            if (idx64) { sN[m2] = ei[2 * ec]; dN[m2] = ei[2 * (E + ec)]; }
            else       { sN[m2] = ei[ec];     dN[m2] = ei[E + ec]; }
          }
        }
      }

      // ---- Issue next mt's gather: latency hides under this epilogue ----
      if (mt < 3) issue(sI[mt + 1], dI[mt + 1], ebase + (mt + 1) * 16 + ln);
      else        issue(sN[0], dN[0], (tile + (int)gridDim.x) * 256 + wv * 64 + ln);

      // ---- Epilogue (wave-private; DPP reductions, no barriers) ----
      f32x4 mu, rs;
      lnstats(acc[0], acc[1], acc[2], acc[3], mu, rs);

      #pragma unroll
      for (int jt = 0; jt < 4; ++jt)
        #pragma unroll
        for (int r = 0; r < 4; ++r) {
          float h = (acc[jt][r] - mu[r]) * rs[r] * g1v[jt] + be1v[jt];
          h = fmaxf(h, NEG_SLOPE * h);
          HB[wv][(quad * 4 + r) * SW2 + ln + 16 * jt] = (short)cvtpk(h, h);
        }
      // wave-private handoff: DS in-order per wave; drain writes then read
      asm volatile("s_waitcnt lgkmcnt(0)" ::: "memory");

      f32x4 acc2[4];
      #pragma unroll
      for (int jt = 0; jt < 4; ++jt) acc2[jt] = (f32x4)(b2v[jt]);
      #pragma unroll
      for (int t2 = 0; t2 < 2; ++t2) {
        short8 a2 = *(const short8*)&HB[wv][ln * SW2 + t2 * 32 + quad * 8];
        #pragma unroll
        for (int jt = 0; jt < 4; ++jt) {
          short8 w2f = *(const short8*)&W2T[(jt * 16 + ln) * SW2 + t2 * 32 + quad * 8];
          acc2[jt] = __builtin_amdgcn_mfma_f32_16x16x32_bf16(
              a2, w2f, acc2[jt], 0, 0, 0);
        }
      }

      f32x4 mu2, rs2;
      lnstats(acc2[0], acc2[1], acc2[2], acc2[3], mu2, rs2);

      f32x4 po = (f32x4)0.f;
      #pragma unroll
      for (int jt = 0; jt < 4; ++jt)
        #pragma unroll
        for (int r = 0; r < 4; ++r) {
          float h = (acc2[jt][r] - mu2[r]) * rs2[r] * g2v[jt] + be2v[jt];
          h = fmaxf(h, NEG_SLOPE * h);
          po[r] = fmaf(h, W3v[jt], po[r]);
        }
      redsum16(po);

      if (ln < 4) {       // lanes 0-3 of each quad store edges quad*4 + ln
        int e = ebase + mt * 16 + quad * 4 + ln;
        if (e < E) {
          float v = (ln == 0) ? po[0] : (ln == 1) ? po[1]
                  : (ln == 2) ? po[2] : po[3];
          out[e] = v + b3s;
        }
      }
    }

    // rotate next-tile indices into place
    #pragma unroll
    for (int m2 = 0; m2 < 4; ++m2) { sI[m2] = sN[m2]; dI[m2] = dN[m2]; }
  }
}

extern "C" void kernel_launch(void* const* d_in, const int* in_sizes, int n_in,
                              void* d_out, int out_size, void* d_ws, size_t ws_size,
                              hipStream_t stream) {
  const float* nf = (const float*)d_in[0];
  const int*   ei = (const int*)d_in[1];
  const float* ea = (const float*)d_in[2];

  const int E = out_size;
  const int ntiles = (E + 255) / 256;
  const int blocks = ntiles < 2048 ? ntiles : 2048;

  edge_mlp_mfma<<<blocks, TPB, 0, stream>>>(
      nf, ei, ea,
      (const float*)d_in[3],  (const float*)d_in[4],
      (const float*)d_in[5],  (const float*)d_in[6],
      (const float*)d_in[7],  (const float*)d_in[8],
      (const float*)d_in[9],  (const float*)d_in[10],
      (const float*)d_in[11], (const float*)d_in[12],
      (float*)d_out, E, ntiles);
}